// Round 4
// baseline (10736.039 us; speedup 1.0000x reference)
//
#include <hip/hip_runtime.h>
#include <cstddef>
#include <cstdint>

#define T256 256

// ---------------- conv1 (1->16, 7x7, relu, maxpool2) ----------------
// one block per image; whole 100x100 image in LDS. fan-in 49: f32 is accurate enough.
__global__ __launch_bounds__(256) void conv1_pool_k(
    const float* __restrict__ x, const float* __restrict__ w,
    const float* __restrict__ bias, float* __restrict__ out)
{
  __shared__ float img[10000];
  __shared__ float wsm[16 * 49];
  __shared__ float bsm[16];
  const int b = blockIdx.x, tid = threadIdx.x;
  for (int i = tid; i < 10000; i += T256) img[i] = x[(size_t)b * 10000 + i];
  for (int i = tid; i < 16 * 49; i += T256) wsm[i] = w[i];
  if (tid < 16) bsm[tid] = bias[tid];
  __syncthreads();
  for (int p = tid; p < 47 * 47; p += T256) {
    const int py = p / 47, px = p % 47;
    const int iy0 = 2 * py, ix0 = 2 * px;
    float win[8][8];
#pragma unroll
    for (int r = 0; r < 8; ++r)
#pragma unroll
      for (int c = 0; c < 8; ++c)
        win[r][c] = img[(iy0 + r) * 100 + (ix0 + c)];
#pragma unroll 2
    for (int oc = 0; oc < 16; ++oc) {
      float m = 0.f;  // relu(max) == max(relu): init 0 handles relu
#pragma unroll
      for (int dy = 0; dy < 2; ++dy)
#pragma unroll
        for (int dx = 0; dx < 2; ++dx) {
          float s = bsm[oc];
#pragma unroll
          for (int ky = 0; ky < 7; ++ky)
#pragma unroll
            for (int kx = 0; kx < 7; ++kx)
              s += win[dy + ky][dx + kx] * wsm[oc * 49 + ky * 7 + kx];
          m = fmaxf(m, s);
        }
      out[((size_t)b * 16 + oc) * 2209 + p] = m;
    }
  }
}

// ---------------- generic direct conv (+relu, optional maxpool2) ----------------
// block = (image b, oc-group og). Per input channel: plane staged in LDS,
// per-thread weights in registers (OCT oc), window in registers.
// Precision: f32 inner dot per ic (short chain), f64 accumulator across ic.
template <int IC, int IH, int IW, int K, int POOL, int PL, int OCT>
__global__ __launch_bounds__(256) void convg_k(
    const float* __restrict__ in, const float* __restrict__ w,
    const float* __restrict__ bias, float* __restrict__ out, int OC)
{
  constexpr int OHC = IH - K + 1, OWC = IW - K + 1;
  constexpr int OH = POOL ? OHC / 2 : OHC;
  constexpr int OW = POOL ? OWC / 2 : OWC;
  constexpr int P = OH * OW;
  constexpr int CH = T256 / PL;       // oc chunks across threads
  constexpr int G = CH * OCT;         // oc per block
  constexpr int NP = (P + PL - 1) / PL;
  constexpr int WR = POOL ? K + 1 : K;
  constexpr int NCV = POOL ? 2 : 1;
  static_assert(CH * PL == 256, "layout");

  __shared__ float plane[IH * IW];
  __shared__ float wsm[G * K * K];
  const int b = blockIdx.x, og = blockIdx.y, tid = threadIdx.x;
  const int pbase = tid % PL, chunk = tid / PL;
  const int ocbase = og * G + chunk * OCT;

  double acc[NP][OCT][NCV * NCV];
#pragma unroll
  for (int a = 0; a < NP; ++a)
#pragma unroll
    for (int o = 0; o < OCT; ++o)
#pragma unroll
      for (int c = 0; c < NCV * NCV; ++c) acc[a][o][c] = 0.0;

  for (int ic = 0; ic < IC; ++ic) {
    __syncthreads();
    for (int i = tid; i < IH * IW; i += T256)
      plane[i] = in[((size_t)b * IC + ic) * (IH * IW) + i];
    for (int i = tid; i < G * K * K; i += T256)
      wsm[i] = w[((size_t)(og * G + i / (K * K)) * IC + ic) * (K * K) + i % (K * K)];
    __syncthreads();
    float wreg[OCT][K * K];
#pragma unroll
    for (int o = 0; o < OCT; ++o)
#pragma unroll
      for (int j = 0; j < K * K; ++j)
        wreg[o][j] = wsm[(chunk * OCT + o) * K * K + j];
#pragma unroll
    for (int np = 0; np < NP; ++np) {
      const int p = pbase + np * PL;
      if (P % PL == 0 || p < P) {
        const int py = p / OW, px = p % OW;
        const int iy0 = py * (POOL ? 2 : 1), ix0 = px * (POOL ? 2 : 1);
        float win[WR][WR];
#pragma unroll
        for (int r = 0; r < WR; ++r)
#pragma unroll
          for (int c = 0; c < WR; ++c)
            win[r][c] = plane[(iy0 + r) * IW + (ix0 + c)];
#pragma unroll
        for (int o = 0; o < OCT; ++o)
#pragma unroll
          for (int dy = 0; dy < NCV; ++dy)
#pragma unroll
            for (int dx = 0; dx < NCV; ++dx) {
              float s = 0.f;  // short f32 chain (<= K*K taps)
#pragma unroll
              for (int ky = 0; ky < K; ++ky)
#pragma unroll
                for (int kx = 0; kx < K; ++kx)
                  s += win[dy + ky][dx + kx] * wreg[o][ky * K + kx];
              acc[np][o][dy * NCV + dx] += (double)s;  // f64 fold per ic
            }
      }
    }
  }
#pragma unroll
  for (int np = 0; np < NP; ++np) {
    const int p = pbase + np * PL;
    if (P % PL == 0 || p < P) {
#pragma unroll
      for (int o = 0; o < OCT; ++o) {
        const int oc = ocbase + o;
        double v;
        if constexpr (POOL == 1) {
          double m01 = fmax(acc[np][o][0], acc[np][o][1]);
          double m23 = fmax(acc[np][o][2], acc[np][o][3]);
          v = fmax(m01, m23);
        } else {
          v = acc[np][o][0];
        }
        v = fmax(v + (double)bias[oc], 0.0);
        out[((size_t)b * OC + oc) * P + p] = (float)v;
      }
    }
  }
}

// ---------------- fp32 tiled GEMM: C[M,N] = act(A[M,K] @ B[N,K]^T + b1 (+b2)) ----------------
// BM=64, BN=32, BK=32, 256 threads, 2x4 micro-tile.
// Precision: f32 inner per BK=32 tile, f64 fold across tiles.
template <int ACT>
__global__ __launch_bounds__(256) void gemm_tn_k(
    const float* __restrict__ A, const float* __restrict__ B,
    const float* __restrict__ b1, const float* __restrict__ b2,
    float* __restrict__ C, int M, int N, int K)
{
  __shared__ float As[32][66];
  __shared__ float Bs[32][36];
  const int bn = blockIdx.x, bm = blockIdx.y, tid = threadIdx.x;
  const int tx = tid & 7, ty = tid >> 3;
  const int m0 = bm * 64, n0 = bn * 32;
  double acc[2][4] = {{0, 0, 0, 0}, {0, 0, 0, 0}};
  for (int k0 = 0; k0 < K; k0 += 32) {
    __syncthreads();
#pragma unroll
    for (int l = 0; l < 8; ++l) {
      int id = tid + l * 256;
      int kk = id & 31, mm = id >> 5;
      As[kk][mm] = A[(size_t)(m0 + mm) * K + (k0 + kk)];
    }
#pragma unroll
    for (int l = 0; l < 4; ++l) {
      int id = tid + l * 256;
      int kk = id & 31, nn = id >> 5;
      Bs[kk][nn] = B[(size_t)(n0 + nn) * K + (k0 + kk)];
    }
    __syncthreads();
    float p[2][4] = {{0.f, 0.f, 0.f, 0.f}, {0.f, 0.f, 0.f, 0.f}};
#pragma unroll
    for (int kk = 0; kk < 32; ++kk) {
      const float2 av = *reinterpret_cast<const float2*>(&As[kk][ty * 2]);
      const float4 bv = *reinterpret_cast<const float4*>(&Bs[kk][tx * 4]);
      p[0][0] += av.x * bv.x; p[0][1] += av.x * bv.y;
      p[0][2] += av.x * bv.z; p[0][3] += av.x * bv.w;
      p[1][0] += av.y * bv.x; p[1][1] += av.y * bv.y;
      p[1][2] += av.y * bv.z; p[1][3] += av.y * bv.w;
    }
#pragma unroll
    for (int i = 0; i < 2; ++i)
#pragma unroll
      for (int j = 0; j < 4; ++j) acc[i][j] += (double)p[i][j];  // f64 fold per tile
  }
#pragma unroll
  for (int i = 0; i < 2; ++i) {
    const int m = m0 + ty * 2 + i;
#pragma unroll
    for (int j = 0; j < 4; ++j) {
      const int n = n0 + tx * 4 + j;
      double v = acc[i][j] + (double)b1[n];
      if (b2) v += (double)b2[n];
      if (ACT == 1) v = 1.0 / (1.0 + exp(-v));
      C[(size_t)m * N + n] = (float)v;
    }
  }
}

// ---------------- persistent LSTM over 512 steps ----------------
// 48 WGs x 8 h-columns each. w_hh slice (32 rows x 384) in LDS.
// Per step: f32 48-tap per-lane dot, f64 cross-lane combine + gate math + cell state.
// Global monotonic barrier once per step; h history lives in d_out (it IS the output).
#define NWG 48
#define CPW 8
__global__ __launch_bounds__(256) void lstm_k(
    const float* __restrict__ gin, const float* __restrict__ whh,
    float* __restrict__ out, unsigned int* __restrict__ bar)
{
  __shared__ float wsm[32][392];  // pad 392: conflict-free for e=8i+lk reads
  __shared__ float hsm[384];
  __shared__ double gsum[32];
  const int wg = blockIdx.x, tid = threadIdx.x;
  const int row = tid >> 3, lk = tid & 7;  // 32 rows x 8 lanes
  for (int idx = tid; idx < 32 * 384; idx += T256) {
    int r = idx / 384, e = idx % 384;
    int gq = r >> 3, gj = r & 7;  // row r = gate gq, local col gj
    wsm[r][e] = whh[((size_t)gq * 384 + wg * CPW + gj) * 384 + e];
  }
  double c = 0.0;  // cell state, owned by threads tid<8
  __syncthreads();
  for (int t = 0; t < 512; ++t) {
    if (t == 0) {
      for (int e = tid; e < 384; e += T256) hsm[e] = 0.f;
    } else {
      for (int e = tid; e < 384; e += T256) hsm[e] = out[(size_t)(t - 1) * 384 + e];
    }
    __syncthreads();
    float s = 0.f;
#pragma unroll
    for (int i = 0; i < 48; ++i) {
      const int e = (i << 3) | lk;
      s += wsm[row][e] * hsm[e];
    }
    double sd = (double)s;  // f64 cross-lane combine
    sd += __shfl_xor(sd, 1);
    sd += __shfl_xor(sd, 2);
    sd += __shfl_xor(sd, 4);
    if (lk == 0) gsum[row] = sd;
    __syncthreads();
    if (tid < CPW) {
      const int j = wg * CPW + tid;
      const double gi = gsum[0 * CPW + tid] + (double)gin[(size_t)t * 1536 + 0 * 384 + j];
      const double gf = gsum[1 * CPW + tid] + (double)gin[(size_t)t * 1536 + 1 * 384 + j];
      const double gg = gsum[2 * CPW + tid] + (double)gin[(size_t)t * 1536 + 2 * 384 + j];
      const double go = gsum[3 * CPW + tid] + (double)gin[(size_t)t * 1536 + 3 * 384 + j];
      const double si = 1.0 / (1.0 + exp(-gi));
      const double sf = 1.0 / (1.0 + exp(-gf));
      const double so = 1.0 / (1.0 + exp(-go));
      c = sf * c + si * tanh(gg);
      out[(size_t)t * 384 + j] = (float)(so * tanh(c));
    }
    __threadfence();  // release: publish h writes to agent scope
    __syncthreads();
    if (tid == 0) {
      __hip_atomic_fetch_add(bar, 1u, __ATOMIC_RELEASE, __HIP_MEMORY_SCOPE_AGENT);
      const unsigned target = (unsigned)NWG * (unsigned)(t + 1);
      while (__hip_atomic_load(bar, __ATOMIC_ACQUIRE, __HIP_MEMORY_SCOPE_AGENT) < target) {
        __builtin_amdgcn_s_sleep(8);
      }
    }
    __syncthreads();
    __threadfence();  // acquire side for ALL threads before reading remote h
  }
}

extern "C" void kernel_launch(void* const* d_in, const int* in_sizes, int n_in,
                              void* d_out, int out_size, void* d_ws, size_t ws_size,
                              hipStream_t stream)
{
  const float* x   = (const float*)d_in[0];
  const float* cw1 = (const float*)d_in[1];
  const float* cb1 = (const float*)d_in[2];
  const float* cw2 = (const float*)d_in[3];
  const float* cb2 = (const float*)d_in[4];
  const float* cw3 = (const float*)d_in[5];
  const float* cb3 = (const float*)d_in[6];
  const float* cw4 = (const float*)d_in[7];
  const float* cb4 = (const float*)d_in[8];
  const float* cw5 = (const float*)d_in[9];
  const float* cb5 = (const float*)d_in[10];
  const float* cw6 = (const float*)d_in[11];
  const float* cb6 = (const float*)d_in[12];
  const float* lw1 = (const float*)d_in[13];
  const float* lb1 = (const float*)d_in[14];
  const float* lw2 = (const float*)d_in[15];
  const float* lb2 = (const float*)d_in[16];
  const float* wih = (const float*)d_in[17];
  const float* whh = (const float*)d_in[18];
  const float* bih = (const float*)d_in[19];
  const float* bhh = (const float*)d_in[20];
  float* out = (float*)d_out;
  char* ws = (char*)d_ws;

  // ---- workspace layout (bytes) — ROUND-3 FIX ----
  // conv1 out = 512*16*2209*4 = 72,384,512 B (was wrongly 72,351,744 = 2208
  // slip -> bufB aliased conv1's tail -> corrupted image 511 -> 0.027 absmax).
  float* bufA = (float*)(ws);                     // cap 72,384,512 (conv1 out)
  float* bufB = (float*)(ws + 72384512);          // cap 51,380,224 (conv4 out)
  float* l1o  = (float*)(ws + 123764736);         // 512x1024
  float* x2   = (float*)(ws + 125861888);         // 512x384
  float* gin  = (float*)(ws + 126648320);         // 512x1536
  unsigned int* bar = (unsigned int*)(ws + 129794048);

  // conv1: (512,1,100,100) -> (512,16,47,47)
  conv1_pool_k<<<512, 256, 0, stream>>>(x, cw1, cb1, bufA);
  // conv2: 16->32, 4x4, pool -> (512,32,22,22)
  convg_k<16, 47, 47, 4, 1, 256, 4><<<dim3(512, 8), 256, 0, stream>>>(bufA, cw2, cb2, bufB, 32);
  // conv3: 32->64, 5x5 -> (512,64,18,18)
  convg_k<32, 22, 22, 5, 0, 128, 4><<<dim3(512, 8), 256, 0, stream>>>(bufB, cw3, cb3, bufA, 64);
  // conv4: 64->128, 5x5 -> (512,128,14,14)
  convg_k<64, 18, 18, 5, 0, 64, 4><<<dim3(512, 8), 256, 0, stream>>>(bufA, cw4, cb4, bufB, 128);
  // conv5: 128->128, 5x5 -> (512,128,10,10)
  convg_k<128, 14, 14, 5, 0, 32, 4><<<dim3(512, 4), 256, 0, stream>>>(bufB, cw5, cb5, bufA, 128);
  // conv6: 128->128, 3x3 -> (512,128,8,8) == (512,8192)
  convg_k<128, 10, 10, 3, 0, 32, 4><<<dim3(512, 4), 256, 0, stream>>>(bufA, cw6, cb6, bufB, 128);
  // linear1: (512,8192)@(1024,8192)^T -> (512,1024)
  gemm_tn_k<0><<<dim3(1024 / 32, 512 / 64), 256, 0, stream>>>(bufB, lw1, lb1, nullptr, l1o, 512, 1024, 8192);
  // linear2+sigmoid: -> (512,384)
  gemm_tn_k<1><<<dim3(384 / 32, 512 / 64), 256, 0, stream>>>(l1o, lw2, lb2, nullptr, x2, 512, 384, 1024);
  // LSTM input precompute: G_in = x2 @ w_ih^T + b_ih + b_hh -> (512,1536)
  gemm_tn_k<0><<<dim3(1536 / 32, 512 / 64), 256, 0, stream>>>(x2, wih, bih, bhh, gin, 512, 1536, 384);
  // barrier counter reset + persistent LSTM
  hipMemsetAsync(bar, 0, 256, stream);
  lstm_k<<<NWG, 256, 0, stream>>>(gin, whh, out, bar);
}